// Round 6
// baseline (113.651 us; speedup 1.0000x reference)
//
#include <hip/hip_runtime.h>
#include <hip/hip_bf16.h>
#include <math.h>

#define N_NODES 8192
#define IN_DIM  512
#define OUT_DIM 512
#define KN      16
#define CAP     128
#define QPB     8

typedef __attribute__((ext_vector_type(8))) short bf16x8;
typedef __attribute__((ext_vector_type(4))) float f32x4;

__device__ __forceinline__ ushort f2bf(float x) {
  __hip_bfloat16 b = __float2bfloat16(x);
  return *reinterpret_cast<ushort*>(&b);
}
__device__ __forceinline__ float bflo(unsigned u) { return __uint_as_float(u << 16); }
__device__ __forceinline__ float bfhi(unsigned u) { return __uint_as_float(u & 0xffff0000u); }

#define GLOAD_LDS16(gp, lp)                                                     \
  __builtin_amdgcn_global_load_lds((const __attribute__((address_space(1))) void*)(gp), \
                                   (__attribute__((address_space(3))) void*)(lp), 16, 0, 0)

// ---------------- prep: h -> A2 (hi|lo bf16) AND f64 G coords, one h pass ----
__global__ __launch_bounds__(256) void prep_kernel(
    const float* __restrict__ h, const float* __restrict__ Wg,
    ushort* __restrict__ A2,
    double* __restrict__ Gx, double* __restrict__ Gy,
    double* __restrict__ Gz, double* __restrict__ Gsq,
    float4* __restrict__ gpk) {
  const int node = (blockIdx.x * 256 + threadIdx.x) >> 6;
  const int lane = threadIdx.x & 63;
  const int k = lane * 8;
  const float* hr = h + (size_t)node * IN_DIM;

  float4 v0 = *(const float4*)&hr[k];
  float4 v1 = *(const float4*)&hr[k + 4];

  ushort h0 = f2bf(v0.x), h1 = f2bf(v0.y), h2 = f2bf(v0.z), h3 = f2bf(v0.w);
  ushort h4 = f2bf(v1.x), h5 = f2bf(v1.y), h6 = f2bf(v1.z), h7 = f2bf(v1.w);
  ushort4 hiA = make_ushort4(h0, h1, h2, h3);
  ushort4 hiB = make_ushort4(h4, h5, h6, h7);
  ushort4 loA = make_ushort4(f2bf(v0.x - bflo((unsigned)h0)), f2bf(v0.y - bflo((unsigned)h1)),
                             f2bf(v0.z - bflo((unsigned)h2)), f2bf(v0.w - bflo((unsigned)h3)));
  ushort4 loB = make_ushort4(f2bf(v1.x - bflo((unsigned)h4)), f2bf(v1.y - bflo((unsigned)h5)),
                             f2bf(v1.z - bflo((unsigned)h6)), f2bf(v1.w - bflo((unsigned)h7)));
  size_t base = (size_t)node * 1024 + k;
  *(ushort4*)&A2[base]           = hiA;
  *(ushort4*)&A2[base + 4]       = hiB;
  *(ushort4*)&A2[base + 512]     = loA;
  *(ushort4*)&A2[base + 512 + 4] = loB;

  float4 w0a = *(const float4*)&Wg[0 * IN_DIM + k];
  float4 w0b = *(const float4*)&Wg[0 * IN_DIM + k + 4];
  float4 w1a = *(const float4*)&Wg[1 * IN_DIM + k];
  float4 w1b = *(const float4*)&Wg[1 * IN_DIM + k + 4];
  float4 w2a = *(const float4*)&Wg[2 * IN_DIM + k];
  float4 w2b = *(const float4*)&Wg[2 * IN_DIM + k + 4];

  double s0 = 0.0, s1 = 0.0, s2 = 0.0;
  s0 += (double)v0.x * w0a.x; s0 += (double)v0.y * w0a.y;
  s0 += (double)v0.z * w0a.z; s0 += (double)v0.w * w0a.w;
  s0 += (double)v1.x * w0b.x; s0 += (double)v1.y * w0b.y;
  s0 += (double)v1.z * w0b.z; s0 += (double)v1.w * w0b.w;
  s1 += (double)v0.x * w1a.x; s1 += (double)v0.y * w1a.y;
  s1 += (double)v0.z * w1a.z; s1 += (double)v0.w * w1a.w;
  s1 += (double)v1.x * w1b.x; s1 += (double)v1.y * w1b.y;
  s1 += (double)v1.z * w1b.z; s1 += (double)v1.w * w1b.w;
  s2 += (double)v0.x * w2a.x; s2 += (double)v0.y * w2a.y;
  s2 += (double)v0.z * w2a.z; s2 += (double)v0.w * w2a.w;
  s2 += (double)v1.x * w2b.x; s2 += (double)v1.y * w2b.y;
  s2 += (double)v1.z * w2b.z; s2 += (double)v1.w * w2b.w;

  #pragma unroll
  for (int off = 32; off; off >>= 1) {
    s0 += __shfl_down(s0, off);
    s1 += __shfl_down(s1, off);
    s2 += __shfl_down(s2, off);
  }
  if (lane == 0) {
    double sq = s0 * s0 + s1 * s1 + s2 * s2;
    Gx[node] = s0; Gy[node] = s1; Gz[node] = s2; Gsq[node] = sq;
    gpk[node] = make_float4((float)s0, (float)s1, (float)s2, -(float)sq);
  }
}

// ---------------- split W -> Bqk (hi, K'=512) and Bv (hi|hi, K'=1024) ----
__global__ __launch_bounds__(256) void split_w(const float* __restrict__ Wq,
                                               const float* __restrict__ Wk,
                                               const float* __restrict__ Wv,
                                               ushort* __restrict__ Bqk,
                                               ushort* __restrict__ Bv) {
  int i = blockIdx.x * 256 + threadIdx.x;    // 1536 rows * 128 float4
  int n  = i >> 7;
  int kc = (i & 127) << 2;
  if (n < 1024) {
    const float* W = (n < 512) ? Wq : Wk;
    int r = n & 511;
    float4 v = *(const float4*)&W[(size_t)r * 512 + kc];
    *(ushort4*)&Bqk[(size_t)n * 512 + kc] =
        make_ushort4(f2bf(v.x), f2bf(v.y), f2bf(v.z), f2bf(v.w));
  } else {
    int r = n - 1024;
    float4 v = *(const float4*)&Wv[(size_t)r * 512 + kc];
    ushort4 hv = make_ushort4(f2bf(v.x), f2bf(v.y), f2bf(v.z), f2bf(v.w));
    *(ushort4*)&Bv[(size_t)r * 1024 + kc]       = hv;
    *(ushort4*)&Bv[(size_t)r * 1024 + 512 + kc] = hv;
  }
}

// ---------------- fused: blocks <768 do MFMA GEMM, blocks >=768 do knn ----
// Independent work, complementary pipes (MFMA vs VALU) -> co-scheduled.
#define GEMM_BLOCKS 768
#define SM_BYTES 20544

__global__ __launch_bounds__(256) void gemm_knn(
    const ushort* __restrict__ A2, const ushort* __restrict__ Bqk,
    const ushort* __restrict__ Bv,
    ushort* __restrict__ Q2, ushort* __restrict__ K2, ushort* __restrict__ V2,
    const float4* __restrict__ gpk,
    const double* __restrict__ Gx, const double* __restrict__ Gy,
    const double* __restrict__ Gz, const double* __restrict__ Gsq,
    int* __restrict__ knn) {
  __shared__ unsigned long long smraw[SM_BYTES / 8];
  const int tid = threadIdx.x, w = tid >> 6, lane = tid & 63;

  if (blockIdx.x < GEMM_BLOCKS) {
    // ---------------- GEMM path ----------------
    const int id = blockIdx.x;
    const int sw = (id & 7) * 96 + (id >> 3);   // XCD-contiguous (768%8==0)
    const int bm = sw / 12, bn = sw % 12;
    const int wr = w >> 1, wc = w & 1;
    const bool isv = (bn >= 8);
    const int  kmax = isv ? 1024 : 512;
    const int  ldb  = isv ? 1024 : 512;
    const ushort* Bb = isv ? (Bv + (size_t)(bn - 8) * 128 * 1024)
                           : (Bqk + (size_t)bn * 128 * 512);
    ushort* lA = (ushort*)smraw;
    ushort* lB = lA + 128 * 32;

    f32x4 acc[4][4] = {};

    const int   srow = w * 32 + (lane >> 2);
    const int   scol = (lane & 3) * 8;
    const size_t gA0 = (size_t)(bm * 128 + srow) * 1024 + scol;
    const size_t gB0 = (size_t)srow * ldb + scol;

    for (int k0 = 0; k0 < kmax; k0 += 32) {
      GLOAD_LDS16(&A2[gA0 + k0],                  &lA[w * 1024]);
      GLOAD_LDS16(&A2[gA0 + 16 * 1024 + k0],      &lA[w * 1024 + 512]);
      GLOAD_LDS16(&Bb[gB0 + k0],                  &lB[w * 1024]);
      GLOAD_LDS16(&Bb[gB0 + (size_t)16 * ldb + k0], &lB[w * 1024 + 512]);
      __syncthreads();

      const int ar = wr * 64 + (lane & 15);
      const int br = wc * 64 + (lane & 15);
      const int kc = (lane >> 4) * 8;
      bf16x8 af[4], bfr[4];
      #pragma unroll
      for (int f = 0; f < 4; ++f) {
        af[f]  = *(const bf16x8*)&lA[(ar + f * 16) * 32 + kc];
        bfr[f] = *(const bf16x8*)&lB[(br + f * 16) * 32 + kc];
      }
      #pragma unroll
      for (int fm = 0; fm < 4; ++fm)
        #pragma unroll
        for (int fn = 0; fn < 4; ++fn)
          acc[fm][fn] = __builtin_amdgcn_mfma_f32_16x16x32_bf16(af[fm], bfr[fn], acc[fm][fn], 0, 0, 0);
      __syncthreads();
    }

    ushort* Cm = isv ? V2 : (bn < 4 ? Q2 : K2);
    const int col  = (isv ? (bn - 8) : (bn & 3)) * 128 + wc * 64 + (lane & 15);
    const int row0 = bm * 128 + wr * 64 + (lane >> 4) * 4;
    #pragma unroll
    for (int fm = 0; fm < 4; ++fm)
      #pragma unroll
      for (int fn = 0; fn < 4; ++fn)
        #pragma unroll
        for (int r = 0; r < 4; ++r)
          Cm[(size_t)(row0 + fm * 16 + r) * 512 + col + fn * 16] = f2bf(acc[fm][fn][r]);
  } else {
    // ---------------- KNN path ----------------
    const int qbase = (blockIdx.x - GEMM_BLOCKS) * QPB;
    float (*s_tmax)[256] = (float(*)[256])smraw;                       // 8192 B
    int   (*s_cand)[CAP] = (int(*)[CAP])((char*)smraw + 8192);         // 4096 B
    double(*s_dval)[CAP] = (double(*)[CAP])((char*)smraw + 12288);     // 8192 B
    int*   s_cnt = (int*)((char*)smraw + 20480);
    float* s_T   = (float*)((char*)smraw + 20512);

    float q2x[QPB], q2y[QPB], q2z[QPB], tmax[QPB];
    #pragma unroll
    for (int s = 0; s < QPB; ++s) {
      float4 qv = gpk[qbase + s];
      q2x[s] = 2.f * qv.x; q2y[s] = 2.f * qv.y; q2z[s] = 2.f * qv.z;
      tmax[s] = -1e30f;
    }
    if (tid < QPB) s_cnt[tid] = 0;

    // Phase A: branchless max scan
    {
      float4 c0 = gpk[tid];
      float4 c1 = gpk[tid + 256];
      for (int i = 0; i < 16; ++i) {
        int nx = ((i + 1) & 15) * 512;
        float4 n0 = gpk[tid + nx];
        float4 n1 = gpk[tid + nx + 256];
        #pragma unroll
        for (int s = 0; s < QPB; ++s) {
          float v0 = fmaf(q2x[s], c0.x, fmaf(q2y[s], c0.y, fmaf(q2z[s], c0.z, c0.w)));
          float v1 = fmaf(q2x[s], c1.x, fmaf(q2y[s], c1.y, fmaf(q2z[s], c1.z, c1.w)));
          tmax[s] = fmaxf(fmaxf(tmax[s], v0), v1);
        }
        c0 = n0; c1 = n1;
      }
    }
    #pragma unroll
    for (int s = 0; s < QPB; ++s) s_tmax[s][tid] = tmax[s];
    __syncthreads();

    // Phase B: exact 16th-of-64 via radix select on monotone float->uint map
    #pragma unroll
    for (int qq = 0; qq < 2; ++qq) {
      int q = w * 2 + qq;
      float v = fmaxf(fmaxf(s_tmax[q][lane], s_tmax[q][lane + 64]),
                      fmaxf(s_tmax[q][lane + 128], s_tmax[q][lane + 192]));
      unsigned b = __float_as_uint(v);
      unsigned u = b ^ ((unsigned)((int)b >> 31) | 0x80000000u);
      unsigned thr = 0;
      for (int bit = 31; bit >= 0; --bit) {
        unsigned cand = thr | (1u << bit);
        unsigned long long m = __ballot(u >= cand);
        if (__popcll(m) >= KN) thr = cand;
      }
      unsigned tb = (thr & 0x80000000u) ? (thr ^ 0x80000000u) : ~thr;
      if (lane == 0) s_T[q] = __uint_as_float(tb);
    }
    __syncthreads();

    // Phase C: rescan (identical FMA chain), collect candidates >= T
    float Ts[QPB];
    #pragma unroll
    for (int s = 0; s < QPB; ++s) Ts[s] = s_T[s];
    {
      float4 c0 = gpk[tid];
      float4 c1 = gpk[tid + 256];
      for (int i = 0; i < 16; ++i) {
        int nx = ((i + 1) & 15) * 512;
        float4 n0 = gpk[tid + nx];
        float4 n1 = gpk[tid + nx + 256];
        int j0 = tid + i * 512, j1 = j0 + 256;
        #pragma unroll
        for (int s = 0; s < QPB; ++s) {
          float v0 = fmaf(q2x[s], c0.x, fmaf(q2y[s], c0.y, fmaf(q2z[s], c0.z, c0.w)));
          float v1 = fmaf(q2x[s], c1.x, fmaf(q2y[s], c1.y, fmaf(q2z[s], c1.z, c1.w)));
          if (v0 >= Ts[s]) { int p = atomicAdd(&s_cnt[s], 1); if (p < CAP) s_cand[s][p] = j0; }
          if (v1 >= Ts[s]) { int p = atomicAdd(&s_cnt[s], 1); if (p < CAP) s_cand[s][p] = j1; }
        }
        c0 = n0; c1 = n1;
      }
    }
    __syncthreads();

    // Phase D: exact f64 scores, rank-by-counting (deterministic total order)
    const int qA = w * 2, qB = qA + 1;
    const int cntA = min(s_cnt[qA], CAP);
    const int cntB = min(s_cnt[qB], CAP);
    int j0a = -1, j1a = -1, j0b = -1, j1b = -1;
    double v0a = 0, v1a = 0, v0b = 0, v1b = 0;
    {
      int gq = qbase + qA;
      double xi = Gx[gq], yi = Gy[gq], zi = Gz[gq], sqi = Gsq[gq];
      if (lane < cntA) {
        j0a = s_cand[qA][lane];
        v0a = 2.0 * (xi * Gx[j0a] + yi * Gy[j0a] + zi * Gz[j0a]) - sqi - Gsq[j0a];
        s_dval[qA][lane] = v0a;
      }
      if (lane + 64 < cntA) {
        j1a = s_cand[qA][lane + 64];
        v1a = 2.0 * (xi * Gx[j1a] + yi * Gy[j1a] + zi * Gz[j1a]) - sqi - Gsq[j1a];
        s_dval[qA][lane + 64] = v1a;
      }
    }
    {
      int gq = qbase + qB;
      double xi = Gx[gq], yi = Gy[gq], zi = Gz[gq], sqi = Gsq[gq];
      if (lane < cntB) {
        j0b = s_cand[qB][lane];
        v0b = 2.0 * (xi * Gx[j0b] + yi * Gy[j0b] + zi * Gz[j0b]) - sqi - Gsq[j0b];
        s_dval[qB][lane] = v0b;
      }
      if (lane + 64 < cntB) {
        j1b = s_cand[qB][lane + 64];
        v1b = 2.0 * (xi * Gx[j1b] + yi * Gy[j1b] + zi * Gz[j1b]) - sqi - Gsq[j1b];
        s_dval[qB][lane + 64] = v1b;
      }
    }
    __syncthreads();
    {
      int r0 = 0, r1 = 0;
      for (int m = 0; m < cntA; ++m) {
        double dv = s_dval[qA][m]; int di = s_cand[qA][m];
        r0 += (dv > v0a) || (dv == v0a && di < j0a);
        r1 += (dv > v1a) || (dv == v1a && di < j1a);
      }
      int gq = qbase + qA;
      if (j0a >= 0 && r0 < KN) knn[gq * KN + r0] = j0a;
      if (j1a >= 0 && r1 < KN) knn[gq * KN + r1] = j1a;
    }
    {
      int r0 = 0, r1 = 0;
      for (int m = 0; m < cntB; ++m) {
        double dv = s_dval[qB][m]; int di = s_cand[qB][m];
        r0 += (dv > v0b) || (dv == v0b && di < j0b);
        r1 += (dv > v1b) || (dv == v1b && di < j1b);
      }
      int gq = qbase + qB;
      if (j0b >= 0 && r0 < KN) knn[gq * KN + r0] = j0b;
      if (j1b >= 0 && r1 < KN) knn[gq * KN + r1] = j1b;
    }
  }
}

// ---------------- attend: per dst node, 16 neighbors, bf16 Q/K/V ---------
__global__ __launch_bounds__(256) void attend_kernel(
    const ushort* __restrict__ Q2, const ushort* __restrict__ K2, const ushort* __restrict__ V2,
    const float4* __restrict__ gpk,
    const int* __restrict__ knn, float* __restrict__ out) {
  const int i    = blockIdx.x;
  const int tid  = threadIdx.x;
  const int wv   = tid >> 6;
  const int lane = tid & 63;

  __shared__ int   s_idx[KN];
  __shared__ float s_w[KN];
  __shared__ float s_se[KN];

  if (tid < KN) s_idx[tid] = knn[i * KN + tid];
  __syncthreads();

  uint4 qa = *(const uint4*)&Q2[(size_t)i * 512 + lane * 8];
  float q0 = bflo(qa.x), q1 = bfhi(qa.x), q2 = bflo(qa.y), q3 = bfhi(qa.y);
  float q4 = bflo(qa.z), q5 = bfhi(qa.z), q6 = bflo(qa.w), q7 = bfhi(qa.w);

  float partial[4];
  #pragma unroll
  for (int s = 0; s < 4; ++s) {
    int src = s_idx[wv * 4 + s];
    uint4 ka = *(const uint4*)&K2[(size_t)src * 512 + lane * 8];
    float acc = q0 * bflo(ka.x);
    acc = fmaf(q1, bfhi(ka.x), acc);
    acc = fmaf(q2, bflo(ka.y), acc);
    acc = fmaf(q3, bfhi(ka.y), acc);
    acc = fmaf(q4, bflo(ka.z), acc);
    acc = fmaf(q5, bfhi(ka.z), acc);
    acc = fmaf(q6, bflo(ka.w), acc);
    acc = fmaf(q7, bfhi(ka.w), acc);
    partial[s] = acc;
  }
  #pragma unroll
  for (int s = 0; s < 4; ++s)
    #pragma unroll
    for (int off = 32; off; off >>= 1) partial[s] += __shfl_down(partial[s], off);

  if (lane == 0) {
    float4 gi = gpk[i];
    #pragma unroll
    for (int s = 0; s < 4; ++s) {
      int e = wv * 4 + s;
      int src = s_idx[e];
      float sc = partial[s] / 22.627417f;
      sc = fminf(fmaxf(sc, -5.f), 5.f);
      float se = expf(sc);
      float4 gs = gpk[src];
      float dx = gi.x - gs.x, dy = gi.y - gs.y, dz = gi.z - gs.z;
      float dd = -sqrtf(fmaf(dx, dx, fmaf(dy, dy, fmaf(dz, dz, 1e-6f))));
      float dc = fminf(fmaxf(dd / 22.627417f, -5.f), 5.f);
      float de = expf(dc);
      s_se[e] = se;
      s_w[e]  = se * de;
    }
  }
  __syncthreads();

  float z = 0.f;
  #pragma unroll
  for (int e = 0; e < KN; ++e) z += s_se[e];

  const int d = tid * 2;
  float a0 = 0.f, a1 = 0.f;
  #pragma unroll
  for (int e = 0; e < KN; ++e) {
    unsigned vv = *(const unsigned*)&V2[(size_t)s_idx[e] * 512 + d];
    a0 = fmaf(s_w[e], bflo(vv), a0);
    a1 = fmaf(s_w[e], bfhi(vv), a1);
  }
  float inv = (z > 0.f) ? (1.f / z) : 1.f;
  float2 o = make_float2(a0 * inv, a1 * inv);
  *(float2*)&out[(size_t)i * 512 + d] = o;
}

extern "C" void kernel_launch(void* const* d_in, const int* in_sizes, int n_in,
                              void* d_out, int out_size, void* d_ws, size_t ws_size,
                              hipStream_t stream) {
  const float* h  = (const float*)d_in[0];
  const float* Wq = (const float*)d_in[1];
  const float* Wk = (const float*)d_in[2];
  const float* Wv = (const float*)d_in[3];
  const float* Wg = (const float*)d_in[4];
  float* out = (float*)d_out;

  char* ws = (char*)d_ws;
  ushort* A2  = (ushort*)(ws);                 // 16 MB
  ushort* Bqk = (ushort*)(ws + (16u << 20));   // 1 MB
  ushort* Bv  = (ushort*)(ws + (17u << 20));   // 1 MB
  ushort* Q2  = (ushort*)(ws + (18u << 20));   // 8 MB
  ushort* K2  = (ushort*)(ws + (26u << 20));   // 8 MB
  ushort* V2  = (ushort*)(ws + (34u << 20));   // 8 MB
  float4* gpk = (float4*)(ws + (42u << 20));   // 128 KB
  double* Gx  = (double*)(ws + (42u << 20) + (1u << 17));
  double* Gy  = Gx + N_NODES;
  double* Gz  = Gy + N_NODES;
  double* Gsq = Gz + N_NODES;
  int*    knn = (int*)(Gsq + N_NODES);         // 512 KB

  hipLaunchKernelGGL(prep_kernel, dim3(N_NODES / 4), dim3(256), 0, stream,
                     h, Wg, A2, Gx, Gy, Gz, Gsq, gpk);
  hipLaunchKernelGGL(split_w, dim3(768), dim3(256), 0, stream,
                     Wq, Wk, Wv, Bqk, Bv);
  hipLaunchKernelGGL(gemm_knn, dim3(GEMM_BLOCKS + N_NODES / QPB), dim3(256), 0, stream,
                     A2, Bqk, Bv, Q2, K2, V2, gpk, Gx, Gy, Gz, Gsq, knn);
  hipLaunchKernelGGL(attend_kernel, dim3(N_NODES), dim3(256), 0, stream,
                     Q2, K2, V2, gpk, knn, out);
}